// Round 14
// baseline (481.011 us; speedup 1.0000x reference)
//
#include <hip/hip_runtime.h>
#include <math.h>

#define Bb 4
#define Tt 2048
#define Dd 256
#define SRr 128
#define Rr 8
#define NA 8
#define NV 16
#define Lf 4096
#define EPSf 1e-5f
#define PI_D 3.14159265358979323846

// ---- workspace layout (floats) ----
#define OFF_TW4R  0
#define OFF_TW4I  (OFF_TW4R + 4096)
#define OFF_PRER  (OFF_TW4I + 4096)
#define OFF_PREI  (OFF_PRER + NV*Tt)
#define OFF_POSR  (OFF_PREI + NV*Tt)
#define OFF_POSI  (OFF_POSR + NV*Tt)
#define OFF_PM2   (OFF_POSI + NV*Tt)
#define OFF_H     (OFF_PM2 + NA*Tt)
#define OFF_WINT  (OFF_H + NV*Lf*2)
#define OFF_WOUTT (OFF_WINT + Dd*SRr)
#define OFF_WOT   (OFF_WOUTT + SRr*Dd)
#define OFF_WTAB  (OFF_WOT + Dd*Dd)
#define OFF_ESUM  (OFF_WTAB + NA*Bb*Tt)
#define OFF_V     (OFF_ESUM + NA*Bb*Tt)
#define OFF_M     (OFF_V + Bb*Dd*Rr)
#define OFF_YT    (OFF_M + Bb*Dd*Rr)
#define OFF_YAC8  (OFF_YT + Bb*Rr*Tt)        // NA * Bb*Rr*Tt (per-z komega slices)
#define OFF_S     (OFF_YAC8 + NA*Bb*Rr*Tt)
#define OFF_XPT   (OFF_S + Bb*Tt*Dd)

// shuffle-based block reduce (256 threads): 2 syncs
__device__ __forceinline__ float block_reduce_sum(float v, float* red, int tid){
  #pragma unroll
  for (int o = 32; o > 0; o >>= 1) v += __shfl_xor(v, o, 64);
  __syncthreads();
  if ((tid & 63) == 0) red[tid >> 6] = v;
  __syncthreads();
  return red[0] + red[1] + red[2] + red[3];
}

// full-wave (64-lane) shuffle sum, no LDS, no syncs
__device__ __forceinline__ float wave_sum(float v){
  #pragma unroll
  for (int o = 32; o > 0; o >>= 1) v += __shfl_xor(v, o, 64);
  return v;
}

// replicate frft_time's parameter math in double (matches Python float math)
__device__ void variant_params(int v, double& s_, double& c_){
  double step = (2.99 - 0.15) / 7.0;
  int idx = v & 7;
  double alpha = (idx == 7) ? 2.99 : (0.15 + (double)idx * step);
  if (v >= 8) alpha = -alpha;
  double a = fmod(alpha + PI_D, 2.0 * PI_D);
  if (a < 0.0) a += 2.0 * PI_D;
  a -= PI_D;
  double sa = sin(a);
  s_ = ((sa >= 0.0) ? 1.0 : -1.0) / fmax(1e-7, fabs(sa));
  c_ = cos(a) / fmax(1e-7, sa);   // NOTE: reference quirk — not abs(sa)!
}

// ---------------- complex helpers / register FFT ----------------
struct cpx { float r, i; };
__device__ __forceinline__ cpx cmul(cpx a, cpx b){ return {a.r*b.r - a.i*b.i, a.r*b.i + a.i*b.r}; }
__device__ __forceinline__ cpx cmulj(cpx a, cpx b){ return {a.r*b.r + a.i*b.i, a.i*b.r - a.r*b.i}; }

__device__ __forceinline__ void fft4(cpx& a, cpx& b, cpx& c, cpx& d, float sgn){
  cpx t0{a.r+c.r, a.i+c.i}, t1{a.r-c.r, a.i-c.i};
  cpx t2{b.r+d.r, b.i+d.i}, t3{b.r-d.r, b.i-d.i};
  a = {t0.r+t2.r, t0.i+t2.i};
  c = {t0.r-t2.r, t0.i-t2.i};
  b = {t1.r - sgn*t3.i, t1.i + sgn*t3.r};   // t1 + sgn*i*t3
  d = {t1.r + sgn*t3.i, t1.i - sgn*t3.r};
}

// 16-point FFT, natural order in/out. ZP=1: inputs x[8..15] are known zero.
template<int ZP>
__device__ __forceinline__ void fft16(cpx x[16], float sgn){
  const float WC[10] = {1.f, 0.92387953251128674f, 0.70710678118654752f, 0.38268343236508977f,
                        0.f, -0.38268343236508977f, -0.70710678118654752f, -0.92387953251128674f,
                        -1.f, -0.92387953251128674f};
  const float WS[10] = {0.f, 0.38268343236508977f, 0.70710678118654752f, 0.92387953251128674f,
                        1.f, 0.92387953251128674f, 0.70710678118654752f, 0.38268343236508977f,
                        0.f, -0.38268343236508977f};
  if (ZP){
    #pragma unroll
    for (int j0 = 0; j0 < 4; ++j0){
      cpx a = x[j0], b = x[j0+4];
      x[j0]    = {a.r + b.r,       a.i + b.i};
      x[j0+4]  = {a.r - sgn*b.i,   a.i + sgn*b.r};
      x[j0+8]  = {a.r - b.r,       a.i - b.i};
      x[j0+12] = {a.r + sgn*b.i,   a.i - sgn*b.r};
    }
  } else {
    #pragma unroll
    for (int j0 = 0; j0 < 4; ++j0)
      fft4(x[j0], x[j0+4], x[j0+8], x[j0+12], sgn);
  }
  #pragma unroll
  for (int j0 = 1; j0 < 4; ++j0){
    #pragma unroll
    for (int p0 = 1; p0 < 4; ++p0){
      int m = j0*p0;
      cpx w{WC[m], sgn*WS[m]};
      x[j0 + 4*p0] = cmul(x[j0 + 4*p0], w);
    }
  }
  #pragma unroll
  for (int p0 = 0; p0 < 4; ++p0)
    fft4(x[4*p0+0], x[4*p0+1], x[4*p0+2], x[4*p0+3], sgn);
  cpx t;
  t=x[1];  x[1]=x[4];   x[4]=t;
  t=x[2];  x[2]=x[8];   x[8]=t;
  t=x[3];  x[3]=x[12];  x[12]=t;
  t=x[6];  x[6]=x[9];   x[9]=t;
  t=x[7];  x[7]=x[13];  x[13]=t;
  t=x[11]; x[11]=x[14]; x[14]=t;
}

// 4096-pt four-step FFT, float2 LDS (pad-272). Input: thread tid holds x[j*256+tid].
// Output: thread tid=(hi,lo) reg r holds X[k], k = hi + 16*lo + 256*r.
template<int ZP>
__device__ __forceinline__ void fft4096c(cpx x[16], float2* sh,
                                         const cpx twA[16], const cpx twB[16],
                                         int tid, float sgn){
  int hi = tid >> 4, lo = tid & 15;
  fft16<ZP>(x, sgn);
  #pragma unroll
  for (int p = 1; p < 16; ++p) x[p] = (sgn < 0.f) ? cmul(x[p], twA[p]) : cmulj(x[p], twA[p]);
  __syncthreads();
  #pragma unroll
  for (int p = 0; p < 16; ++p){ sh[p*272 + 17*hi + lo] = make_float2(x[p].r, x[p].i); }
  __syncthreads();
  #pragma unroll
  for (int u = 0; u < 16; ++u){ float2 v = sh[hi*272 + 17*u + lo]; x[u] = {v.x, v.y}; }
  fft16<0>(x, sgn);
  #pragma unroll
  for (int q = 1; q < 16; ++q) x[q] = (sgn < 0.f) ? cmul(x[q], twB[q]) : cmulj(x[q], twB[q]);
  __syncthreads();
  #pragma unroll
  for (int q = 0; q < 16; ++q){ sh[hi*272 + 17*q + lo] = make_float2(x[q].r, x[q].i); }
  __syncthreads();
  #pragma unroll
  for (int v = 0; v < 16; ++v){ float2 t = sh[hi*272 + 17*lo + v]; x[v] = {t.x, t.y}; }
  fft16<0>(x, sgn);
}

// Half-LDS variant: float buffer (17408B/group), split re/im sweeps, pad-272 index
// math (VGPR-safe, verified R12). ltid is the caller's 0..255 group-local id; the
// __syncthreads inside sync the WHOLE block — valid because groups run symmetric code.
template<int ZP>
__device__ __forceinline__ void fft4096h(cpx x[16], float* sh,
                                         const cpx twA[16], const cpx twB[16],
                                         int ltid, float sgn){
  int hi = ltid >> 4, lo = ltid & 15;
  fft16<ZP>(x, sgn);
  #pragma unroll
  for (int p = 1; p < 16; ++p) x[p] = (sgn < 0.f) ? cmul(x[p], twA[p]) : cmulj(x[p], twA[p]);
  __syncthreads();
  #pragma unroll
  for (int p = 0; p < 16; ++p) sh[p*272 + 17*hi + lo] = x[p].r;
  __syncthreads();
  #pragma unroll
  for (int u = 0; u < 16; ++u) x[u].r = sh[hi*272 + 17*u + lo];
  __syncthreads();
  #pragma unroll
  for (int p = 0; p < 16; ++p) sh[p*272 + 17*hi + lo] = x[p].i;
  __syncthreads();
  #pragma unroll
  for (int u = 0; u < 16; ++u) x[u].i = sh[hi*272 + 17*u + lo];
  fft16<0>(x, sgn);
  #pragma unroll
  for (int q = 1; q < 16; ++q) x[q] = (sgn < 0.f) ? cmul(x[q], twB[q]) : cmulj(x[q], twB[q]);
  __syncthreads();
  #pragma unroll
  for (int q = 0; q < 16; ++q) sh[hi*272 + 17*q + lo] = x[q].r;
  __syncthreads();
  #pragma unroll
  for (int v = 0; v < 16; ++v) x[v].r = sh[hi*272 + 17*lo + v];
  __syncthreads();
  #pragma unroll
  for (int q = 0; q < 16; ++q) sh[hi*272 + 17*q + lo] = x[q].i;
  __syncthreads();
  #pragma unroll
  for (int v = 0; v < 16; ++v) x[v].i = sh[hi*272 + 17*lo + v];
  fft16<0>(x, sgn);
}

// ---------------- merged setup: transposes + TW4 + chirp tables + H spectra + ESUM zero ----
__global__ __launch_bounds__(256) void k_setup(const float* Win, const float* Wout,
                                               const float* Wo, float* ws){
  __shared__ float2 sh[16*272];
  int blk = blockIdx.x, tid = threadIdx.x;
  int id = blk*256 + tid;                      // 65536 ids
  { int d = id & (Dd-1); int k = id >> 8; ws[OFF_WOT + id] = Wo[d*Dd + k]; }
  ws[OFF_ESUM + id] = 0.f;                     // replaces hipMemsetAsync
  if (id < Dd*SRr){
    int c = id & (SRr-1); int k = id >> 7;
    ws[OFF_WINT + id] = Win[c*Dd + k];
    int d2 = id & (Dd-1); int k2 = id >> 8;
    ws[OFF_WOUTT + id] = Wout[d2*SRr + k2];
  }
  if (id < 4096){
    double ang = -2.0 * PI_D * (double)id / (double)Lf;
    ws[OFF_TW4R + id] = (float)cos(ang);
    ws[OFF_TW4I + id] = (float)sin(ang);
  }
  if (blk >= NV) return;
  int v = blk;
  double s_, c_;
  variant_params(v, s_, c_);
  double dt = 2.0 / (double)(Tt - 1);
  {
    double cf = (double)(float)c_;
    double rmag = sqrt(1.0 + cf * cf);
    double pr = sqrt((rmag + 1.0) * 0.5);
    double pim = ((cf >= 0.0) ? -1.0 : 1.0) * sqrt(fmax(0.0, (rmag - 1.0) * 0.5));
    double cps = PI_D * (c_ + s_);
    double sc = dt / (double)Lf;
    for (int k = tid; k < Tt; k += 256){
      double t = (k == Tt - 1) ? 1.0 : ((double)k * dt - 1.0);
      double th = cps * (t * t);
      double cr = cos(th), ci = sin(th);
      ws[OFF_PRER + v*Tt + k] = (float)cr;
      ws[OFF_PREI + v*Tt + k] = (float)ci;
      float por = (float)((pr*cr - pim*ci) * sc);
      float poi = (float)((pr*ci + pim*cr) * sc);
      ws[OFF_POSR + v*Tt + k] = por;
      ws[OFF_POSI + v*Tt + k] = poi;
      if (v < NA) ws[OFF_PM2 + v*Tt + k] = por*por + poi*poi;
    }
  }
  int hi = tid >> 4, lo = tid & 15;
  int base = hi + 16*lo;
  cpx twA[16], twB[16];
  #pragma unroll
  for (int p = 0; p < 16; ++p){
    double aA = -2.0 * PI_D * (double)((tid * p) & 4095) / (double)Lf;
    double aB = -2.0 * PI_D * (double)((16 * lo * p) & 4095) / (double)Lf;
    twA[p] = {(float)cos(aA), (float)sin(aA)};
    twB[p] = {(float)cos(aB), (float)sin(aB)};
  }
  double ns = -(PI_D * s_);
  cpx x[16];
  #pragma unroll
  for (int j = 0; j < 16; ++j){
    int n = j*256 + tid;
    if (n == 2048){ x[j] = {0.f, 0.f}; continue; }
    int m = (n <= 2047) ? n : (n - 4096);
    double md = (double)m * dt;
    double th = ns * (md * md);
    x[j] = {(float)cos(th), (float)sin(th)};
  }
  fft4096c<0>(x, sh, twA, twB, tid, -1.f);
  #pragma unroll
  for (int r = 0; r < 16; ++r){
    int k = base + 256*r;
    ws[OFF_H + (v*Lf + k)*2 + 0] = x[r].r;
    ws[OFF_H + (v*Lf + k)*2 + 1] = x[r].i;
  }
}

// ---------------- fused shift: u = gelu(x@WinT), s = u@WoutT + b, xprime ----------------
__global__ __launch_bounds__(256) void k_shift(const float* x, const float* bsh, float* ws){
  __shared__ float xs[16][Dd];
  __shared__ float us[16][SRr];
  int tid = threadIdx.x;
  int g0 = blockIdx.x * 16;
  int b = g0 >> 11, t0 = g0 & (Tt - 1);
  #pragma unroll
  for (int row = 0; row < 16; ++row)
    xs[row][tid] = x[(g0 + row)*Dd + tid];
  __syncthreads();
  int col = tid & 127, rowgrp = tid >> 7;
  {
    float acc[8];
    #pragma unroll
    for (int rr = 0; rr < 8; ++rr) acc[rr] = 0.f;
    const float* WT = ws + OFF_WINT;
    for (int k = 0; k < Dd; ++k){
      float w = WT[k*SRr + col];
      #pragma unroll
      for (int rr = 0; rr < 8; ++rr)
        acc[rr] = fmaf(xs[rowgrp*8 + rr][k], w, acc[rr]);
    }
    #pragma unroll
    for (int rr = 0; rr < 8; ++rr){
      float a = acc[rr];
      us[rowgrp*8 + rr][col] = 0.5f * a * (1.0f + erff(a * 0.70710678118654752f));
    }
  }
  __syncthreads();
  float sacc[16];
  float bv = bsh[tid];
  #pragma unroll
  for (int row = 0; row < 16; ++row) sacc[row] = bv;
  const float* WT2 = ws + OFF_WOUTT;
  for (int k = 0; k < SRr; ++k){
    float w = WT2[k*Dd + tid];
    #pragma unroll
    for (int row = 0; row < 16; ++row)
      sacc[row] = fmaf(us[row][k], w, sacc[row]);
  }
  float xp[16];
  #pragma unroll
  for (int row = 0; row < 16; ++row){
    float xv = xs[row][tid];
    float anc = (tid == 0) ? 1.0f : 0.0f;
    ws[OFF_S + (g0 + row)*Dd + tid] = sacc[row];
    xp[row] = xv - anc + sacc[row];
  }
  float* xpt = ws + OFF_XPT + ((size_t)(b*Dd + tid))*Tt + t0;
  #pragma unroll
  for (int q = 0; q < 4; ++q)
    *reinterpret_cast<float4*>(xpt + 4*q) = make_float4(xp[4*q], xp[4*q+1], xp[4*q+2], xp[4*q+3]);
}

// ---------------- FrFT energy weights: 512 threads = 2 independent 256-thread FFT groups ----
// Forces 8 waves/CU co-resident (intra-block guarantee) to hide fft16 dependency stalls.
__global__ __launch_bounds__(512) void k_weights(float* ws){
  __shared__ float sh2[2*16*272];        // 2 x 17408 B
  int tid = threadIdx.x;
  int grp = tid >> 8, ltid = tid & 255;
  float* sh = sh2 + grp*(16*272);
  int chunk = blockIdx.x, b = blockIdx.y, z = blockIdx.z;
  int hi = ltid >> 4, lo = ltid & 15;
  int base = hi + 16*lo;                 // k = base + 256*r
  const float* tw4r = ws + OFF_TW4R; const float* tw4i = ws + OFF_TW4I;
  cpx twA[16], twB[16];
  #pragma unroll
  for (int p = 0; p < 16; ++p){
    int iA = ltid * p;     twA[p] = {tw4r[iA], tw4i[iA]};
    int iB = 16 * lo * p;  twB[p] = {tw4r[iB], tw4i[iB]};
  }
  const float* prer = ws + OFF_PRER + z*Tt;
  const float* prei = ws + OFF_PREI + z*Tt;
  const float* pm2  = ws + OFF_PM2  + z*Tt;
  const float* Hv   = ws + OFF_H    + z*Lf*2;
  float e[16];
  #pragma unroll
  for (int r = 0; r < 16; ++r) e[r] = 0.f;
  for (int cc = 0; cc < 8; ++cc){
    int c = chunk*16 + grp*8 + cc;       // block covers 16 channels, 8 per group
    const float* xcol = ws + OFF_XPT + ((size_t)(b*Dd + c))*Tt;
    cpx x[16];
    #pragma unroll
    for (int j = 0; j < 8; ++j){
      int t = j*256 + ltid;
      float xv = xcol[t];
      x[j] = {xv * prer[t], xv * prei[t]};
    }
    #pragma unroll
    for (int j = 8; j < 16; ++j) x[j] = {0.f, 0.f};
    fft4096h<1>(x, sh, twA, twB, ltid, -1.f);
    #pragma unroll
    for (int r = 0; r < 16; ++r){
      int k = base + 256*r;
      cpx h{Hv[2*k], Hv[2*k+1]};
      x[r] = cmul(x[r], h);
    }
    // redistribute spectrum to j-major layout (split re/im):
    // reg r holds G[k], k=base+256r -> plane r, position 17*lo+hi
    __syncthreads();
    #pragma unroll
    for (int r = 0; r < 16; ++r) sh[r*272 + 17*lo + hi] = x[r].r;
    __syncthreads();
    #pragma unroll
    for (int j = 0; j < 16; ++j) x[j].r = sh[j*272 + 17*hi + lo];
    __syncthreads();
    #pragma unroll
    for (int r = 0; r < 16; ++r) sh[r*272 + 17*lo + hi] = x[r].i;
    __syncthreads();
    #pragma unroll
    for (int j = 0; j < 16; ++j) x[j].i = sh[j*272 + 17*hi + lo];
    fft4096h<0>(x, sh, twA, twB, ltid, +1.f);
    #pragma unroll
    for (int r = 0; r < 16; ++r){
      int k = base + 256*r;
      if (k >= 2047 && k < 4095){
        int t = k - 2047;
        e[r] += pm2[t] * (x[r].r*x[r].r + x[r].i*x[r].i);
      }
    }
  }
  float* Ez = ws + OFF_ESUM + (z*Bb + b)*Tt;
  #pragma unroll
  for (int r = 0; r < 16; ++r){
    int k = base + 256*r;
    if (k >= 2047 && k < 4095) atomicAdd(&Ez[k - 2047], e[r]);
  }
}

__global__ void k_wnorm(float* ws){
  __shared__ float red[4];
  int b = blockIdx.x, z = blockIdx.y, tid = threadIdx.x;
  const float* Ez = ws + OFF_ESUM + (z*Bb + b)*Tt;
  float* wz = ws + OFF_WTAB + (z*Bb + b)*Tt;
  float wr[8]; float psum = 0.f;
  #pragma unroll
  for (int k = 0; k < 8; ++k){
    float Ea = Ez[tid + k*256] * (1.0f / (float)Dd);
    wr[k] = sqrtf(Ea + 1e-6f);
    psum += wr[k];
  }
  float tot = block_reduce_sum(psum, red, tid);
  float inv = 1.0f / (tot / (float)Tt + 1e-6f);
  #pragma unroll
  for (int k = 0; k < 8; ++k) wz[tid + k*256] = wr[k] * inv;
}

// ---------------- subspace iteration ----------------
__global__ void k_traces(float* ws){
  __shared__ float Vl[Dd*Rr];
  int tile = blockIdx.x, b = blockIdx.y, tid = threadIdx.x;
  for (int i = tid; i < Dd*Rr; i += 256) Vl[i] = ws[OFF_V + b*Dd*Rr + i];
  __syncthreads();
  int t = tile*256 + tid;
  float acc[Rr];
  #pragma unroll
  for (int r = 0; r < Rr; ++r) acc[r] = 0.f;
  const float* xp = ws + OFF_XPT + ((size_t)(b*Dd))*Tt + t;
  for (int d = 0; d < Dd; ++d){
    float xv = xp[(size_t)d*Tt];
    #pragma unroll
    for (int r = 0; r < Rr; ++r) acc[r] = fmaf(xv, Vl[d*Rr + r], acc[r]);
  }
  #pragma unroll
  for (int r = 0; r < Rr; ++r) ws[OFF_YT + (b*Rr + r)*Tt + t] = acc[r];
}

// per-z output slices (no atomics, no memset); useXPT=1: read Y directly from XPT rows (V0 = E0)
__global__ __launch_bounds__(256) void k_komega(float* ws, int useXPT){
  __shared__ float2 sh[16*272];
  int tid = threadIdx.x;
  int rr = blockIdx.x, b = blockIdx.y, z = blockIdx.z;
  int hi = tid >> 4, lo = tid & 15;
  int base = hi + 16*lo;
  int v1 = z, v2 = z + NA;
  const float* tw4r = ws + OFF_TW4R; const float* tw4i = ws + OFF_TW4I;
  cpx twA[16], twB[16];
  #pragma unroll
  for (int p = 0; p < 16; ++p){
    int iA = tid * p;      twA[p] = {tw4r[iA], tw4i[iA]};
    int iB = 16 * lo * p;  twB[p] = {tw4r[iB], tw4i[iB]};
  }
  const float* prer1 = ws + OFF_PRER + v1*Tt; const float* prei1 = ws + OFF_PREI + v1*Tt;
  const float* posr1 = ws + OFF_POSR + v1*Tt; const float* posi1 = ws + OFF_POSI + v1*Tt;
  const float* prer2 = ws + OFF_PRER + v2*Tt; const float* prei2 = ws + OFF_PREI + v2*Tt;
  const float* posr2 = ws + OFF_POSR + v2*Tt; const float* posi2 = ws + OFF_POSI + v2*Tt;
  const float* H1 = ws + OFF_H + v1*Lf*2;
  const float* H2 = ws + OFF_H + v2*Lf*2;
  const float* wz = ws + OFF_WTAB + (z*Bb + b)*Tt;
  const float* ycol = useXPT ? (ws + OFF_XPT + ((size_t)(b*Dd + rr))*Tt)
                             : (ws + OFF_YT + ((size_t)(b*Rr + rr))*Tt);
  float* yac = ws + OFF_YAC8 + ((size_t)((z*Bb + b)*Rr + rr))*Tt;
  cpx x[16];
  #pragma unroll
  for (int j = 0; j < 8; ++j){
    int t = j*256 + tid;
    float yv = ycol[t];
    x[j] = {yv * prer1[t], yv * prei1[t]};
  }
  #pragma unroll
  for (int j = 8; j < 16; ++j) x[j] = {0.f, 0.f};
  fft4096c<1>(x, sh, twA, twB, tid, -1.f);
  #pragma unroll
  for (int r = 0; r < 16; ++r){ int k = base + 256*r; cpx h{H1[2*k], H1[2*k+1]}; x[r] = cmul(x[r], h); }
  __syncthreads();
  #pragma unroll
  for (int r = 0; r < 16; ++r){ sh[r*272 + 17*lo + hi] = make_float2(x[r].r, x[r].i); }
  __syncthreads();
  #pragma unroll
  for (int j = 0; j < 16; ++j){ float2 v = sh[j*272 + 17*hi + lo]; x[j] = {v.x, v.y}; }
  fft4096c<0>(x, sh, twA, twB, tid, +1.f);
  __syncthreads();
  #pragma unroll
  for (int r = 0; r < 16; ++r){
    int k = base + 256*r;
    if (k >= 2047 && k < 4095){
      int t = k - 2047;
      float cr = x[r].r, ci = x[r].i;
      float wv = wz[t];
      float yar = (posr1[t]*cr - posi1[t]*ci) * wv;
      float yai = (posr1[t]*ci + posi1[t]*cr) * wv;
      float gr = yar*prer2[t] - yai*prei2[t];
      float gi = yar*prei2[t] + yai*prer2[t];
      int a = (t >> 8)*272 + 17*((t >> 4) & 15) + (t & 15);
      sh[a] = make_float2(gr, gi);
    }
  }
  __syncthreads();
  #pragma unroll
  for (int j = 0; j < 8; ++j){ float2 v = sh[j*272 + 17*hi + lo]; x[j] = {v.x, v.y}; }
  #pragma unroll
  for (int j = 8; j < 16; ++j) x[j] = {0.f, 0.f};
  fft4096c<1>(x, sh, twA, twB, tid, -1.f);
  #pragma unroll
  for (int r = 0; r < 16; ++r){ int k = base + 256*r; cpx h{H2[2*k], H2[2*k+1]}; x[r] = cmul(x[r], h); }
  __syncthreads();
  #pragma unroll
  for (int r = 0; r < 16; ++r){ sh[r*272 + 17*lo + hi] = make_float2(x[r].r, x[r].i); }
  __syncthreads();
  #pragma unroll
  for (int j = 0; j < 16; ++j){ float2 v = sh[j*272 + 17*hi + lo]; x[j] = {v.x, v.y}; }
  fft4096c<0>(x, sh, twA, twB, tid, +1.f);
  #pragma unroll
  for (int r = 0; r < 16; ++r){
    int k = base + 256*r;
    if (k >= 2047 && k < 4095){
      int t = k - 2047;
      yac[t] = posr2[t]*x[r].r - posi2[t]*x[r].i;
    }
  }
}

// sum the 8 z-slices into YT
__global__ void k_ysum(float* ws){
  int i = (blockIdx.x*256 + threadIdx.x) * 4;   // 64 blocks
  float4 acc = make_float4(0.f, 0.f, 0.f, 0.f);
  #pragma unroll
  for (int z = 0; z < NA; ++z){
    float4 v = *reinterpret_cast<const float4*>(ws + OFF_YAC8 + (size_t)z*Bb*Rr*Tt + i);
    acc.x += v.x; acc.y += v.y; acc.z += v.z; acc.w += v.w;
  }
  *reinterpret_cast<float4*>(ws + OFF_YT + i) = acc;
}

__global__ void k_zm(float* ws, int useIdent){
  __shared__ float red[4];
  int d = blockIdx.x, b = blockIdx.y, tid = threadIdx.x;
  const float* xcol = ws + OFF_XPT + ((size_t)(b*Dd + d))*Tt;
  float xv[8];
  #pragma unroll
  for (int j = 0; j < 8; ++j) xv[j] = xcol[tid + 256*j];
  for (int r = 0; r < Rr; ++r){
    const float* ycol = ws + OFF_YT + (b*Rr + r)*Tt;
    float p = 0.f;
    #pragma unroll
    for (int j = 0; j < 8; ++j) p = fmaf(xv[j], ycol[tid + 256*j], p);
    float tot = block_reduce_sum(p, red, tid);
    if (tid == 0){
      float zval = tot / (float)(Tt * NA);
      float vprev = useIdent ? ((d == r) ? 1.f : 0.f) : ws[OFF_V + (b*Dd + d)*Rr + r];
      ws[OFF_M + (b*Dd + d)*Rr + r] = zval + EPSf * vprev;
    }
  }
}

// one wave per batch; MGS entirely in registers + shuffles, zero __syncthreads
__global__ __launch_bounds__(64) void k_mgs(float* ws){
  int b = blockIdx.x, lane = threadIdx.x;
  float m[Rr][4];
  #pragma unroll
  for (int r = 0; r < Rr; ++r){
    #pragma unroll
    for (int q = 0; q < 4; ++q)
      m[r][q] = ws[OFF_M + (size_t)(b*Dd + lane + 64*q)*Rr + r];
  }
  #pragma unroll
  for (int r = 0; r < Rr; ++r){
    #pragma unroll
    for (int j = 0; j < r; ++j){
      float p = 0.f;
      #pragma unroll
      for (int q = 0; q < 4; ++q) p = fmaf(m[j][q], m[r][q], p);
      float dotv = wave_sum(p);
      #pragma unroll
      for (int q = 0; q < 4; ++q) m[r][q] = fmaf(-dotv, m[j][q], m[r][q]);
    }
    float p = 0.f;
    #pragma unroll
    for (int q = 0; q < 4; ++q) p = fmaf(m[r][q], m[r][q], p);
    float n2 = wave_sum(p);
    float s = sqrtf(n2);
    #pragma unroll
    for (int q = 0; q < 4; ++q) m[r][q] = m[r][q] / s;
  }
  #pragma unroll
  for (int r = 0; r < Rr; ++r){
    #pragma unroll
    for (int q = 0; q < 4; ++q)
      ws[OFF_V + (size_t)(b*Dd + lane + 64*q)*Rr + r] = m[r][q];
  }
}

// ---------------- fused epilogue ----------------
__global__ __launch_bounds__(256) void k_out(const float* x, const float* g, const float* be,
                                             float* ws, float* out){
  __shared__ float hs[16][Dd + 1];
  __shared__ float ytl[16][Rr];
  __shared__ float mv_mu[16], mv_rs[16];
  int tid = threadIdx.x;
  int g0 = blockIdx.x * 16;
  int b = g0 >> 11, t0 = g0 & (Tt - 1);
  if (tid < 128){
    int row = tid >> 3, r = tid & 7;
    ytl[row][r] = ws[OFF_YT + (b*Rr + r)*Tt + t0 + row];
  }
  float vr[Rr];
  {
    const float4* Vb = reinterpret_cast<const float4*>(ws + OFF_V + (b*Dd + tid)*Rr);
    float4 v0 = Vb[0], v1 = Vb[1];
    vr[0]=v0.x; vr[1]=v0.y; vr[2]=v0.z; vr[3]=v0.w;
    vr[4]=v1.x; vr[5]=v1.y; vr[6]=v1.z; vr[7]=v1.w;
  }
  __syncthreads();
  #pragma unroll
  for (int row = 0; row < 16; ++row){
    float acc = 0.f;
    #pragma unroll
    for (int r = 0; r < Rr; ++r) acc = fmaf(ytl[row][r], vr[r], acc);
    acc -= ws[OFF_S + (g0 + row)*Dd + tid];
    if (tid == 0) acc += 1.0f;
    hs[row][tid] = acc;
  }
  __syncthreads();
  float acc[16];
  #pragma unroll
  for (int row = 0; row < 16; ++row) acc[row] = x[(g0 + row)*Dd + tid];
  const float* WT = ws + OFF_WOT;
  for (int k = 0; k < Dd; ++k){
    float w = WT[k*Dd + tid];
    #pragma unroll
    for (int row = 0; row < 16; ++row)
      acc[row] = fmaf(hs[row][k], w, acc[row]);
  }
  __syncthreads();
  #pragma unroll
  for (int row = 0; row < 16; ++row) hs[row][tid] = acc[row];
  __syncthreads();
  {
    int row = tid >> 4, j = tid & 15;
    float yv[16]; float sum = 0.f;
    #pragma unroll
    for (int mth = 0; mth < 16; ++mth){ yv[mth] = hs[row][j + 16*mth]; sum += yv[mth]; }
    #pragma unroll
    for (int o = 8; o > 0; o >>= 1) sum += __shfl_xor(sum, o, 16);
    float mu = sum * (1.0f / (float)Dd);
    float ssq = 0.f;
    #pragma unroll
    for (int mth = 0; mth < 16; ++mth){ float d = yv[mth] - mu; ssq = fmaf(d, d, ssq); }
    #pragma unroll
    for (int o = 8; o > 0; o >>= 1) ssq += __shfl_xor(ssq, o, 16);
    if (j == 0){ mv_mu[row] = mu; mv_rs[row] = rsqrtf(ssq * (1.0f / (float)Dd) + 1e-5f); }
  }
  __syncthreads();
  float gg = g[tid], bb = be[tid];
  #pragma unroll
  for (int row = 0; row < 16; ++row)
    out[(g0 + row)*Dd + tid] = (acc[row] - mv_mu[row]) * mv_rs[row] * gg + bb;
}

extern "C" void kernel_launch(void* const* d_in, const int* in_sizes, int n_in,
                              void* d_out, int out_size, void* d_ws, size_t ws_size,
                              hipStream_t stream){
  (void)in_sizes; (void)n_in; (void)out_size; (void)ws_size;
  const float* x    = (const float*)d_in[0];
  const float* Win  = (const float*)d_in[1];
  const float* Wout = (const float*)d_in[2];
  const float* bsh  = (const float*)d_in[3];
  const float* Wo   = (const float*)d_in[4];
  const float* g    = (const float*)d_in[5];
  const float* be   = (const float*)d_in[6];
  float* ws  = (float*)d_ws;
  float* out = (float*)d_out;

  hipLaunchKernelGGL(k_setup, dim3(256), dim3(256), 0, stream, Win, Wout, Wo, ws);
  hipLaunchKernelGGL(k_shift, dim3(Bb*Tt/16), dim3(256), 0, stream, x, bsh, ws);
  hipLaunchKernelGGL(k_weights, dim3(Dd/16, Bb, NA), dim3(512), 0, stream, ws);
  hipLaunchKernelGGL(k_wnorm, dim3(Bb, NA), dim3(256), 0, stream, ws);
  // iteration 0: V0 = E0 (identity block) — komega reads XPT rows directly
  hipLaunchKernelGGL(k_komega, dim3(Rr, Bb, NA), dim3(256), 0, stream, ws, 1);
  hipLaunchKernelGGL(k_ysum, dim3(64), dim3(256), 0, stream, ws);
  hipLaunchKernelGGL(k_zm, dim3(Dd, Bb), dim3(256), 0, stream, ws, 1);
  hipLaunchKernelGGL(k_mgs, dim3(Bb), dim3(64), 0, stream, ws);
  // iteration 1
  hipLaunchKernelGGL(k_traces, dim3(Tt/256, Bb), dim3(256), 0, stream, ws);
  hipLaunchKernelGGL(k_komega, dim3(Rr, Bb, NA), dim3(256), 0, stream, ws, 0);
  hipLaunchKernelGGL(k_ysum, dim3(64), dim3(256), 0, stream, ws);
  hipLaunchKernelGGL(k_zm, dim3(Dd, Bb), dim3(256), 0, stream, ws, 0);
  hipLaunchKernelGGL(k_mgs, dim3(Bb), dim3(64), 0, stream, ws);
  // final traces + epilogue
  hipLaunchKernelGGL(k_traces, dim3(Tt/256, Bb), dim3(256), 0, stream, ws);
  hipLaunchKernelGGL(k_out, dim3(Bb*Tt/16), dim3(256), 0, stream, x, g, be, ws, out);
}

// Round 15
// 420.540 us; speedup vs baseline: 1.1438x; 1.1438x over previous
//
#include <hip/hip_runtime.h>
#include <math.h>

#define Bb 4
#define Tt 2048
#define Dd 256
#define SRr 128
#define Rr 8
#define NA 8
#define NV 16
#define Lf 4096
#define EPSf 1e-5f
#define PI_D 3.14159265358979323846

// ---- workspace layout (floats) ----
#define OFF_TW4R  0
#define OFF_TW4I  (OFF_TW4R + 4096)
#define OFF_PRER  (OFF_TW4I + 4096)
#define OFF_PREI  (OFF_PRER + NV*Tt)
#define OFF_POSR  (OFF_PREI + NV*Tt)
#define OFF_POSI  (OFF_POSR + NV*Tt)
#define OFF_PM2   (OFF_POSI + NV*Tt)
#define OFF_H     (OFF_PM2 + NA*Tt)
#define OFF_WINT  (OFF_H + NV*Lf*2)
#define OFF_WOUTT (OFF_WINT + Dd*SRr)
#define OFF_WOT   (OFF_WOUTT + SRr*Dd)
#define OFF_WTAB  (OFF_WOT + Dd*Dd)
#define OFF_ESUM  (OFF_WTAB + NA*Bb*Tt)
#define OFF_V     (OFF_ESUM + NA*Bb*Tt)
#define OFF_M     (OFF_V + Bb*Dd*Rr)
#define OFF_YT    (OFF_M + Bb*Dd*Rr)
#define OFF_YAC8  (OFF_YT + Bb*Rr*Tt)        // NA * Bb*Rr*Tt (per-z komega slices)
#define OFF_S     (OFF_YAC8 + NA*Bb*Rr*Tt)
#define OFF_XPT   (OFF_S + Bb*Tt*Dd)

// shuffle-based block reduce (256 threads): 2 syncs
__device__ __forceinline__ float block_reduce_sum(float v, float* red, int tid){
  #pragma unroll
  for (int o = 32; o > 0; o >>= 1) v += __shfl_xor(v, o, 64);
  __syncthreads();
  if ((tid & 63) == 0) red[tid >> 6] = v;
  __syncthreads();
  return red[0] + red[1] + red[2] + red[3];
}

// full-wave (64-lane) shuffle sum, no LDS, no syncs
__device__ __forceinline__ float wave_sum(float v){
  #pragma unroll
  for (int o = 32; o > 0; o >>= 1) v += __shfl_xor(v, o, 64);
  return v;
}

// replicate frft_time's parameter math in double (matches Python float math)
__device__ void variant_params(int v, double& s_, double& c_){
  double step = (2.99 - 0.15) / 7.0;
  int idx = v & 7;
  double alpha = (idx == 7) ? 2.99 : (0.15 + (double)idx * step);
  if (v >= 8) alpha = -alpha;
  double a = fmod(alpha + PI_D, 2.0 * PI_D);
  if (a < 0.0) a += 2.0 * PI_D;
  a -= PI_D;
  double sa = sin(a);
  s_ = ((sa >= 0.0) ? 1.0 : -1.0) / fmax(1e-7, fabs(sa));
  c_ = cos(a) / fmax(1e-7, sa);   // NOTE: reference quirk — not abs(sa)!
}

// ---------------- complex helpers / register FFT ----------------
struct cpx { float r, i; };
__device__ __forceinline__ cpx cmul(cpx a, cpx b){ return {a.r*b.r - a.i*b.i, a.r*b.i + a.i*b.r}; }
__device__ __forceinline__ cpx cmulj(cpx a, cpx b){ return {a.r*b.r + a.i*b.i, a.i*b.r - a.r*b.i}; }

__device__ __forceinline__ void fft4(cpx& a, cpx& b, cpx& c, cpx& d, float sgn){
  cpx t0{a.r+c.r, a.i+c.i}, t1{a.r-c.r, a.i-c.i};
  cpx t2{b.r+d.r, b.i+d.i}, t3{b.r-d.r, b.i-d.i};
  a = {t0.r+t2.r, t0.i+t2.i};
  c = {t0.r-t2.r, t0.i-t2.i};
  b = {t1.r - sgn*t3.i, t1.i + sgn*t3.r};   // t1 + sgn*i*t3
  d = {t1.r + sgn*t3.i, t1.i - sgn*t3.r};
}

// 16-point FFT, natural order in/out. ZP=1: inputs x[8..15] are known zero.
template<int ZP>
__device__ __forceinline__ void fft16(cpx x[16], float sgn){
  const float WC[10] = {1.f, 0.92387953251128674f, 0.70710678118654752f, 0.38268343236508977f,
                        0.f, -0.38268343236508977f, -0.70710678118654752f, -0.92387953251128674f,
                        -1.f, -0.92387953251128674f};
  const float WS[10] = {0.f, 0.38268343236508977f, 0.70710678118654752f, 0.92387953251128674f,
                        1.f, 0.92387953251128674f, 0.70710678118654752f, 0.38268343236508977f,
                        0.f, -0.38268343236508977f};
  if (ZP){
    #pragma unroll
    for (int j0 = 0; j0 < 4; ++j0){
      cpx a = x[j0], b = x[j0+4];
      x[j0]    = {a.r + b.r,       a.i + b.i};
      x[j0+4]  = {a.r - sgn*b.i,   a.i + sgn*b.r};
      x[j0+8]  = {a.r - b.r,       a.i - b.i};
      x[j0+12] = {a.r + sgn*b.i,   a.i - sgn*b.r};
    }
  } else {
    #pragma unroll
    for (int j0 = 0; j0 < 4; ++j0)
      fft4(x[j0], x[j0+4], x[j0+8], x[j0+12], sgn);
  }
  #pragma unroll
  for (int j0 = 1; j0 < 4; ++j0){
    #pragma unroll
    for (int p0 = 1; p0 < 4; ++p0){
      int m = j0*p0;
      cpx w{WC[m], sgn*WS[m]};
      x[j0 + 4*p0] = cmul(x[j0 + 4*p0], w);
    }
  }
  #pragma unroll
  for (int p0 = 0; p0 < 4; ++p0)
    fft4(x[4*p0+0], x[4*p0+1], x[4*p0+2], x[4*p0+3], sgn);
  cpx t;
  t=x[1];  x[1]=x[4];   x[4]=t;
  t=x[2];  x[2]=x[8];   x[8]=t;
  t=x[3];  x[3]=x[12];  x[12]=t;
  t=x[6];  x[6]=x[9];   x[9]=t;
  t=x[7];  x[7]=x[13];  x[13]=t;
  t=x[11]; x[11]=x[14]; x[14]=t;
}

// 4096-pt four-step FFT, float2 LDS (pad-272). Input: thread tid holds x[j*256+tid].
// Output: thread tid=(hi,lo) reg r holds X[k], k = hi + 16*lo + 256*r.
template<int ZP>
__device__ __forceinline__ void fft4096c(cpx x[16], float2* sh,
                                         const cpx twA[16], const cpx twB[16],
                                         int tid, float sgn){
  int hi = tid >> 4, lo = tid & 15;
  fft16<ZP>(x, sgn);
  #pragma unroll
  for (int p = 1; p < 16; ++p) x[p] = (sgn < 0.f) ? cmul(x[p], twA[p]) : cmulj(x[p], twA[p]);
  __syncthreads();
  #pragma unroll
  for (int p = 0; p < 16; ++p){ sh[p*272 + 17*hi + lo] = make_float2(x[p].r, x[p].i); }
  __syncthreads();
  #pragma unroll
  for (int u = 0; u < 16; ++u){ float2 v = sh[hi*272 + 17*u + lo]; x[u] = {v.x, v.y}; }
  fft16<0>(x, sgn);
  #pragma unroll
  for (int q = 1; q < 16; ++q) x[q] = (sgn < 0.f) ? cmul(x[q], twB[q]) : cmulj(x[q], twB[q]);
  __syncthreads();
  #pragma unroll
  for (int q = 0; q < 16; ++q){ sh[hi*272 + 17*q + lo] = make_float2(x[q].r, x[q].i); }
  __syncthreads();
  #pragma unroll
  for (int v = 0; v < 16; ++v){ float2 t = sh[hi*272 + 17*lo + v]; x[v] = {t.x, t.y}; }
  fft16<0>(x, sgn);
}

// ---------------- merged setup: transposes + TW4 + chirp tables + H spectra + ESUM zero ----
__global__ __launch_bounds__(256) void k_setup(const float* Win, const float* Wout,
                                               const float* Wo, float* ws){
  __shared__ float2 sh[16*272];
  int blk = blockIdx.x, tid = threadIdx.x;
  int id = blk*256 + tid;                      // 65536 ids
  { int d = id & (Dd-1); int k = id >> 8; ws[OFF_WOT + id] = Wo[d*Dd + k]; }
  ws[OFF_ESUM + id] = 0.f;                     // replaces hipMemsetAsync
  if (id < Dd*SRr){
    int c = id & (SRr-1); int k = id >> 7;
    ws[OFF_WINT + id] = Win[c*Dd + k];
    int d2 = id & (Dd-1); int k2 = id >> 8;
    ws[OFF_WOUTT + id] = Wout[d2*SRr + k2];
  }
  if (id < 4096){
    double ang = -2.0 * PI_D * (double)id / (double)Lf;
    ws[OFF_TW4R + id] = (float)cos(ang);
    ws[OFF_TW4I + id] = (float)sin(ang);
  }
  if (blk >= NV) return;
  int v = blk;
  double s_, c_;
  variant_params(v, s_, c_);
  double dt = 2.0 / (double)(Tt - 1);
  {
    double cf = (double)(float)c_;
    double rmag = sqrt(1.0 + cf * cf);
    double pr = sqrt((rmag + 1.0) * 0.5);
    double pim = ((cf >= 0.0) ? -1.0 : 1.0) * sqrt(fmax(0.0, (rmag - 1.0) * 0.5));
    double cps = PI_D * (c_ + s_);
    double sc = dt / (double)Lf;
    for (int k = tid; k < Tt; k += 256){
      double t = (k == Tt - 1) ? 1.0 : ((double)k * dt - 1.0);
      double th = cps * (t * t);
      double cr = cos(th), ci = sin(th);
      ws[OFF_PRER + v*Tt + k] = (float)cr;
      ws[OFF_PREI + v*Tt + k] = (float)ci;
      float por = (float)((pr*cr - pim*ci) * sc);
      float poi = (float)((pr*ci + pim*cr) * sc);
      ws[OFF_POSR + v*Tt + k] = por;
      ws[OFF_POSI + v*Tt + k] = poi;
      if (v < NA) ws[OFF_PM2 + v*Tt + k] = por*por + poi*poi;
    }
  }
  int hi = tid >> 4, lo = tid & 15;
  int base = hi + 16*lo;
  cpx twA[16], twB[16];
  #pragma unroll
  for (int p = 0; p < 16; ++p){
    double aA = -2.0 * PI_D * (double)((tid * p) & 4095) / (double)Lf;
    double aB = -2.0 * PI_D * (double)((16 * lo * p) & 4095) / (double)Lf;
    twA[p] = {(float)cos(aA), (float)sin(aA)};
    twB[p] = {(float)cos(aB), (float)sin(aB)};
  }
  double ns = -(PI_D * s_);
  cpx x[16];
  #pragma unroll
  for (int j = 0; j < 16; ++j){
    int n = j*256 + tid;
    if (n == 2048){ x[j] = {0.f, 0.f}; continue; }
    int m = (n <= 2047) ? n : (n - 4096);
    double md = (double)m * dt;
    double th = ns * (md * md);
    x[j] = {(float)cos(th), (float)sin(th)};
  }
  fft4096c<0>(x, sh, twA, twB, tid, -1.f);
  #pragma unroll
  for (int r = 0; r < 16; ++r){
    int k = base + 256*r;
    ws[OFF_H + (v*Lf + k)*2 + 0] = x[r].r;
    ws[OFF_H + (v*Lf + k)*2 + 1] = x[r].i;
  }
}

// ---------------- fused shift: u = gelu(x@WinT), s = u@WoutT + b, xprime ----------------
__global__ __launch_bounds__(256) void k_shift(const float* x, const float* bsh, float* ws){
  __shared__ float xs[16][Dd];
  __shared__ float us[16][SRr];
  int tid = threadIdx.x;
  int g0 = blockIdx.x * 16;
  int b = g0 >> 11, t0 = g0 & (Tt - 1);
  #pragma unroll
  for (int row = 0; row < 16; ++row)
    xs[row][tid] = x[(g0 + row)*Dd + tid];
  __syncthreads();
  int col = tid & 127, rowgrp = tid >> 7;
  {
    float acc[8];
    #pragma unroll
    for (int rr = 0; rr < 8; ++rr) acc[rr] = 0.f;
    const float* WT = ws + OFF_WINT;
    for (int k = 0; k < Dd; ++k){
      float w = WT[k*SRr + col];
      #pragma unroll
      for (int rr = 0; rr < 8; ++rr)
        acc[rr] = fmaf(xs[rowgrp*8 + rr][k], w, acc[rr]);
    }
    #pragma unroll
    for (int rr = 0; rr < 8; ++rr){
      float a = acc[rr];
      us[rowgrp*8 + rr][col] = 0.5f * a * (1.0f + erff(a * 0.70710678118654752f));
    }
  }
  __syncthreads();
  float sacc[16];
  float bv = bsh[tid];
  #pragma unroll
  for (int row = 0; row < 16; ++row) sacc[row] = bv;
  const float* WT2 = ws + OFF_WOUTT;
  for (int k = 0; k < SRr; ++k){
    float w = WT2[k*Dd + tid];
    #pragma unroll
    for (int row = 0; row < 16; ++row)
      sacc[row] = fmaf(us[row][k], w, sacc[row]);
  }
  float xp[16];
  #pragma unroll
  for (int row = 0; row < 16; ++row){
    float xv = xs[row][tid];
    float anc = (tid == 0) ? 1.0f : 0.0f;
    ws[OFF_S + (g0 + row)*Dd + tid] = sacc[row];
    xp[row] = xv - anc + sacc[row];
  }
  float* xpt = ws + OFF_XPT + ((size_t)(b*Dd + tid))*Tt + t0;
  #pragma unroll
  for (int q = 0; q < 4; ++q)
    *reinterpret_cast<float4*>(xpt + 4*q) = make_float4(xp[4*q], xp[4*q+1], xp[4*q+2], xp[4*q+3]);
}

// ---------------- FrFT energy weights (8 channels/block, R10/R13-proven form) ----------------
__global__ __launch_bounds__(256) void k_weights(float* ws){
  __shared__ float2 sh[16*272];
  int tid = threadIdx.x;
  int chunk = blockIdx.x, b = blockIdx.y, z = blockIdx.z;
  int hi = tid >> 4, lo = tid & 15;
  int base = hi + 16*lo;                 // k = base + 256*r
  const float* tw4r = ws + OFF_TW4R; const float* tw4i = ws + OFF_TW4I;
  cpx twA[16], twB[16];
  #pragma unroll
  for (int p = 0; p < 16; ++p){
    int iA = tid * p;      twA[p] = {tw4r[iA], tw4i[iA]};
    int iB = 16 * lo * p;  twB[p] = {tw4r[iB], tw4i[iB]};
  }
  const float* prer = ws + OFF_PRER + z*Tt;
  const float* prei = ws + OFF_PREI + z*Tt;
  const float* pm2  = ws + OFF_PM2  + z*Tt;
  const float* Hv   = ws + OFF_H    + z*Lf*2;
  float e[16];
  #pragma unroll
  for (int r = 0; r < 16; ++r) e[r] = 0.f;
  for (int cc = 0; cc < 8; ++cc){
    int c = chunk*8 + cc;
    const float* xcol = ws + OFF_XPT + ((size_t)(b*Dd + c))*Tt;
    cpx x[16];
    #pragma unroll
    for (int j = 0; j < 8; ++j){
      int t = j*256 + tid;
      float xv = xcol[t];
      x[j] = {xv * prer[t], xv * prei[t]};
    }
    #pragma unroll
    for (int j = 8; j < 16; ++j) x[j] = {0.f, 0.f};
    fft4096c<1>(x, sh, twA, twB, tid, -1.f);
    #pragma unroll
    for (int r = 0; r < 16; ++r){
      int k = base + 256*r;
      cpx h{Hv[2*k], Hv[2*k+1]};
      x[r] = cmul(x[r], h);
    }
    // redistribute spectrum to j-major layout: reg r holds G[k], k=base+256r
    __syncthreads();
    #pragma unroll
    for (int r = 0; r < 16; ++r){ sh[r*272 + 17*lo + hi] = make_float2(x[r].r, x[r].i); }
    __syncthreads();
    #pragma unroll
    for (int j = 0; j < 16; ++j){ float2 v = sh[j*272 + 17*hi + lo]; x[j] = {v.x, v.y}; }
    fft4096c<0>(x, sh, twA, twB, tid, +1.f);
    #pragma unroll
    for (int r = 0; r < 16; ++r){
      int k = base + 256*r;
      if (k >= 2047 && k < 4095){
        int t = k - 2047;
        e[r] += pm2[t] * (x[r].r*x[r].r + x[r].i*x[r].i);
      }
    }
  }
  float* Ez = ws + OFF_ESUM + (z*Bb + b)*Tt;
  #pragma unroll
  for (int r = 0; r < 16; ++r){
    int k = base + 256*r;
    if (k >= 2047 && k < 4095) atomicAdd(&Ez[k - 2047], e[r]);
  }
}

__global__ void k_wnorm(float* ws){
  __shared__ float red[4];
  int b = blockIdx.x, z = blockIdx.y, tid = threadIdx.x;
  const float* Ez = ws + OFF_ESUM + (z*Bb + b)*Tt;
  float* wz = ws + OFF_WTAB + (z*Bb + b)*Tt;
  float wr[8]; float psum = 0.f;
  #pragma unroll
  for (int k = 0; k < 8; ++k){
    float Ea = Ez[tid + k*256] * (1.0f / (float)Dd);
    wr[k] = sqrtf(Ea + 1e-6f);
    psum += wr[k];
  }
  float tot = block_reduce_sum(psum, red, tid);
  float inv = 1.0f / (tot / (float)Tt + 1e-6f);
  #pragma unroll
  for (int k = 0; k < 8; ++k) wz[tid + k*256] = wr[k] * inv;
}

// ---------------- subspace iteration ----------------
__global__ void k_traces(float* ws){
  __shared__ float Vl[Dd*Rr];
  int tile = blockIdx.x, b = blockIdx.y, tid = threadIdx.x;
  for (int i = tid; i < Dd*Rr; i += 256) Vl[i] = ws[OFF_V + b*Dd*Rr + i];
  __syncthreads();
  int t = tile*256 + tid;
  float acc[Rr];
  #pragma unroll
  for (int r = 0; r < Rr; ++r) acc[r] = 0.f;
  const float* xp = ws + OFF_XPT + ((size_t)(b*Dd))*Tt + t;
  for (int d = 0; d < Dd; ++d){
    float xv = xp[(size_t)d*Tt];
    #pragma unroll
    for (int r = 0; r < Rr; ++r) acc[r] = fmaf(xv, Vl[d*Rr + r], acc[r]);
  }
  #pragma unroll
  for (int r = 0; r < Rr; ++r) ws[OFF_YT + (b*Rr + r)*Tt + t] = acc[r];
}

// per-z output slices (no atomics, no memset); useXPT=1: read Y directly from XPT rows (V0 = E0)
__global__ __launch_bounds__(256) void k_komega(float* ws, int useXPT){
  __shared__ float2 sh[16*272];
  int tid = threadIdx.x;
  int rr = blockIdx.x, b = blockIdx.y, z = blockIdx.z;
  int hi = tid >> 4, lo = tid & 15;
  int base = hi + 16*lo;
  int v1 = z, v2 = z + NA;
  const float* tw4r = ws + OFF_TW4R; const float* tw4i = ws + OFF_TW4I;
  cpx twA[16], twB[16];
  #pragma unroll
  for (int p = 0; p < 16; ++p){
    int iA = tid * p;      twA[p] = {tw4r[iA], tw4i[iA]};
    int iB = 16 * lo * p;  twB[p] = {tw4r[iB], tw4i[iB]};
  }
  const float* prer1 = ws + OFF_PRER + v1*Tt; const float* prei1 = ws + OFF_PREI + v1*Tt;
  const float* posr1 = ws + OFF_POSR + v1*Tt; const float* posi1 = ws + OFF_POSI + v1*Tt;
  const float* prer2 = ws + OFF_PRER + v2*Tt; const float* prei2 = ws + OFF_PREI + v2*Tt;
  const float* posr2 = ws + OFF_POSR + v2*Tt; const float* posi2 = ws + OFF_POSI + v2*Tt;
  const float* H1 = ws + OFF_H + v1*Lf*2;
  const float* H2 = ws + OFF_H + v2*Lf*2;
  const float* wz = ws + OFF_WTAB + (z*Bb + b)*Tt;
  const float* ycol = useXPT ? (ws + OFF_XPT + ((size_t)(b*Dd + rr))*Tt)
                             : (ws + OFF_YT + ((size_t)(b*Rr + rr))*Tt);
  float* yac = ws + OFF_YAC8 + ((size_t)((z*Bb + b)*Rr + rr))*Tt;
  cpx x[16];
  #pragma unroll
  for (int j = 0; j < 8; ++j){
    int t = j*256 + tid;
    float yv = ycol[t];
    x[j] = {yv * prer1[t], yv * prei1[t]};
  }
  #pragma unroll
  for (int j = 8; j < 16; ++j) x[j] = {0.f, 0.f};
  fft4096c<1>(x, sh, twA, twB, tid, -1.f);
  #pragma unroll
  for (int r = 0; r < 16; ++r){ int k = base + 256*r; cpx h{H1[2*k], H1[2*k+1]}; x[r] = cmul(x[r], h); }
  __syncthreads();
  #pragma unroll
  for (int r = 0; r < 16; ++r){ sh[r*272 + 17*lo + hi] = make_float2(x[r].r, x[r].i); }
  __syncthreads();
  #pragma unroll
  for (int j = 0; j < 16; ++j){ float2 v = sh[j*272 + 17*hi + lo]; x[j] = {v.x, v.y}; }
  fft4096c<0>(x, sh, twA, twB, tid, +1.f);
  __syncthreads();
  #pragma unroll
  for (int r = 0; r < 16; ++r){
    int k = base + 256*r;
    if (k >= 2047 && k < 4095){
      int t = k - 2047;
      float cr = x[r].r, ci = x[r].i;
      float wv = wz[t];
      float yar = (posr1[t]*cr - posi1[t]*ci) * wv;
      float yai = (posr1[t]*ci + posi1[t]*cr) * wv;
      float gr = yar*prer2[t] - yai*prei2[t];
      float gi = yar*prei2[t] + yai*prer2[t];
      int a = (t >> 8)*272 + 17*((t >> 4) & 15) + (t & 15);
      sh[a] = make_float2(gr, gi);
    }
  }
  __syncthreads();
  #pragma unroll
  for (int j = 0; j < 8; ++j){ float2 v = sh[j*272 + 17*hi + lo]; x[j] = {v.x, v.y}; }
  #pragma unroll
  for (int j = 8; j < 16; ++j) x[j] = {0.f, 0.f};
  fft4096c<1>(x, sh, twA, twB, tid, -1.f);
  #pragma unroll
  for (int r = 0; r < 16; ++r){ int k = base + 256*r; cpx h{H2[2*k], H2[2*k+1]}; x[r] = cmul(x[r], h); }
  __syncthreads();
  #pragma unroll
  for (int r = 0; r < 16; ++r){ sh[r*272 + 17*lo + hi] = make_float2(x[r].r, x[r].i); }
  __syncthreads();
  #pragma unroll
  for (int j = 0; j < 16; ++j){ float2 v = sh[j*272 + 17*hi + lo]; x[j] = {v.x, v.y}; }
  fft4096c<0>(x, sh, twA, twB, tid, +1.f);
  #pragma unroll
  for (int r = 0; r < 16; ++r){
    int k = base + 256*r;
    if (k >= 2047 && k < 4095){
      int t = k - 2047;
      yac[t] = posr2[t]*x[r].r - posi2[t]*x[r].i;
    }
  }
}

// sum the 8 z-slices into YT
__global__ void k_ysum(float* ws){
  int i = (blockIdx.x*256 + threadIdx.x) * 4;   // 64 blocks
  float4 acc = make_float4(0.f, 0.f, 0.f, 0.f);
  #pragma unroll
  for (int z = 0; z < NA; ++z){
    float4 v = *reinterpret_cast<const float4*>(ws + OFF_YAC8 + (size_t)z*Bb*Rr*Tt + i);
    acc.x += v.x; acc.y += v.y; acc.z += v.z; acc.w += v.w;
  }
  *reinterpret_cast<float4*>(ws + OFF_YT + i) = acc;
}

__global__ void k_zm(float* ws, int useIdent){
  __shared__ float red[4];
  int d = blockIdx.x, b = blockIdx.y, tid = threadIdx.x;
  const float* xcol = ws + OFF_XPT + ((size_t)(b*Dd + d))*Tt;
  float xv[8];
  #pragma unroll
  for (int j = 0; j < 8; ++j) xv[j] = xcol[tid + 256*j];
  for (int r = 0; r < Rr; ++r){
    const float* ycol = ws + OFF_YT + (b*Rr + r)*Tt;
    float p = 0.f;
    #pragma unroll
    for (int j = 0; j < 8; ++j) p = fmaf(xv[j], ycol[tid + 256*j], p);
    float tot = block_reduce_sum(p, red, tid);
    if (tid == 0){
      float zval = tot / (float)(Tt * NA);
      float vprev = useIdent ? ((d == r) ? 1.f : 0.f) : ws[OFF_V + (b*Dd + d)*Rr + r];
      ws[OFF_M + (b*Dd + d)*Rr + r] = zval + EPSf * vprev;
    }
  }
}

// one wave per batch; MGS entirely in registers + shuffles, zero __syncthreads
__global__ __launch_bounds__(64) void k_mgs(float* ws){
  int b = blockIdx.x, lane = threadIdx.x;
  float m[Rr][4];
  #pragma unroll
  for (int r = 0; r < Rr; ++r){
    #pragma unroll
    for (int q = 0; q < 4; ++q)
      m[r][q] = ws[OFF_M + (size_t)(b*Dd + lane + 64*q)*Rr + r];
  }
  #pragma unroll
  for (int r = 0; r < Rr; ++r){
    #pragma unroll
    for (int j = 0; j < r; ++j){
      float p = 0.f;
      #pragma unroll
      for (int q = 0; q < 4; ++q) p = fmaf(m[j][q], m[r][q], p);
      float dotv = wave_sum(p);
      #pragma unroll
      for (int q = 0; q < 4; ++q) m[r][q] = fmaf(-dotv, m[j][q], m[r][q]);
    }
    float p = 0.f;
    #pragma unroll
    for (int q = 0; q < 4; ++q) p = fmaf(m[r][q], m[r][q], p);
    float n2 = wave_sum(p);
    float s = sqrtf(n2);
    #pragma unroll
    for (int q = 0; q < 4; ++q) m[r][q] = m[r][q] / s;
  }
  #pragma unroll
  for (int r = 0; r < Rr; ++r){
    #pragma unroll
    for (int q = 0; q < 4; ++q)
      ws[OFF_V + (size_t)(b*Dd + lane + 64*q)*Rr + r] = m[r][q];
  }
}

// ---------------- fused epilogue ----------------
__global__ __launch_bounds__(256) void k_out(const float* x, const float* g, const float* be,
                                             float* ws, float* out){
  __shared__ float hs[16][Dd + 1];
  __shared__ float ytl[16][Rr];
  __shared__ float mv_mu[16], mv_rs[16];
  int tid = threadIdx.x;
  int g0 = blockIdx.x * 16;
  int b = g0 >> 11, t0 = g0 & (Tt - 1);
  if (tid < 128){
    int row = tid >> 3, r = tid & 7;
    ytl[row][r] = ws[OFF_YT + (b*Rr + r)*Tt + t0 + row];
  }
  float vr[Rr];
  {
    const float4* Vb = reinterpret_cast<const float4*>(ws + OFF_V + (b*Dd + tid)*Rr);
    float4 v0 = Vb[0], v1 = Vb[1];
    vr[0]=v0.x; vr[1]=v0.y; vr[2]=v0.z; vr[3]=v0.w;
    vr[4]=v1.x; vr[5]=v1.y; vr[6]=v1.z; vr[7]=v1.w;
  }
  __syncthreads();
  #pragma unroll
  for (int row = 0; row < 16; ++row){
    float acc = 0.f;
    #pragma unroll
    for (int r = 0; r < Rr; ++r) acc = fmaf(ytl[row][r], vr[r], acc);
    acc -= ws[OFF_S + (g0 + row)*Dd + tid];
    if (tid == 0) acc += 1.0f;
    hs[row][tid] = acc;
  }
  __syncthreads();
  float acc[16];
  #pragma unroll
  for (int row = 0; row < 16; ++row) acc[row] = x[(g0 + row)*Dd + tid];
  const float* WT = ws + OFF_WOT;
  for (int k = 0; k < Dd; ++k){
    float w = WT[k*Dd + tid];
    #pragma unroll
    for (int row = 0; row < 16; ++row)
      acc[row] = fmaf(hs[row][k], w, acc[row]);
  }
  __syncthreads();
  #pragma unroll
  for (int row = 0; row < 16; ++row) hs[row][tid] = acc[row];
  __syncthreads();
  {
    int row = tid >> 4, j = tid & 15;
    float yv[16]; float sum = 0.f;
    #pragma unroll
    for (int mth = 0; mth < 16; ++mth){ yv[mth] = hs[row][j + 16*mth]; sum += yv[mth]; }
    #pragma unroll
    for (int o = 8; o > 0; o >>= 1) sum += __shfl_xor(sum, o, 16);
    float mu = sum * (1.0f / (float)Dd);
    float ssq = 0.f;
    #pragma unroll
    for (int mth = 0; mth < 16; ++mth){ float d = yv[mth] - mu; ssq = fmaf(d, d, ssq); }
    #pragma unroll
    for (int o = 8; o > 0; o >>= 1) ssq += __shfl_xor(ssq, o, 16);
    if (j == 0){ mv_mu[row] = mu; mv_rs[row] = rsqrtf(ssq * (1.0f / (float)Dd) + 1e-5f); }
  }
  __syncthreads();
  float gg = g[tid], bb = be[tid];
  #pragma unroll
  for (int row = 0; row < 16; ++row)
    out[(g0 + row)*Dd + tid] = (acc[row] - mv_mu[row]) * mv_rs[row] * gg + bb;
}

extern "C" void kernel_launch(void* const* d_in, const int* in_sizes, int n_in,
                              void* d_out, int out_size, void* d_ws, size_t ws_size,
                              hipStream_t stream){
  (void)in_sizes; (void)n_in; (void)out_size; (void)ws_size;
  const float* x    = (const float*)d_in[0];
  const float* Win  = (const float*)d_in[1];
  const float* Wout = (const float*)d_in[2];
  const float* bsh  = (const float*)d_in[3];
  const float* Wo   = (const float*)d_in[4];
  const float* g    = (const float*)d_in[5];
  const float* be   = (const float*)d_in[6];
  float* ws  = (float*)d_ws;
  float* out = (float*)d_out;

  hipLaunchKernelGGL(k_setup, dim3(256), dim3(256), 0, stream, Win, Wout, Wo, ws);
  hipLaunchKernelGGL(k_shift, dim3(Bb*Tt/16), dim3(256), 0, stream, x, bsh, ws);
  hipLaunchKernelGGL(k_weights, dim3(Dd/8, Bb, NA), dim3(256), 0, stream, ws);
  hipLaunchKernelGGL(k_wnorm, dim3(Bb, NA), dim3(256), 0, stream, ws);
  // iteration 0: V0 = E0 (identity block) — komega reads XPT rows directly
  hipLaunchKernelGGL(k_komega, dim3(Rr, Bb, NA), dim3(256), 0, stream, ws, 1);
  hipLaunchKernelGGL(k_ysum, dim3(64), dim3(256), 0, stream, ws);
  hipLaunchKernelGGL(k_zm, dim3(Dd, Bb), dim3(256), 0, stream, ws, 1);
  hipLaunchKernelGGL(k_mgs, dim3(Bb), dim3(64), 0, stream, ws);
  // iteration 1
  hipLaunchKernelGGL(k_traces, dim3(Tt/256, Bb), dim3(256), 0, stream, ws);
  hipLaunchKernelGGL(k_komega, dim3(Rr, Bb, NA), dim3(256), 0, stream, ws, 0);
  hipLaunchKernelGGL(k_ysum, dim3(64), dim3(256), 0, stream, ws);
  hipLaunchKernelGGL(k_zm, dim3(Dd, Bb), dim3(256), 0, stream, ws, 0);
  hipLaunchKernelGGL(k_mgs, dim3(Bb), dim3(64), 0, stream, ws);
  // final traces + epilogue
  hipLaunchKernelGGL(k_traces, dim3(Tt/256, Bb), dim3(256), 0, stream, ws);
  hipLaunchKernelGGL(k_out, dim3(Bb*Tt/16), dim3(256), 0, stream, x, g, be, ws, out);
}